// Round 4
// baseline (235.487 us; speedup 1.0000x reference)
//
#include <hip/hip_runtime.h>

// Pipeline:
//  1) cvt_all: query,key,Wq,Wk,Wv f32 -> bf16 (single launch)
//  2) gemm_all: all 3 projections in one launch (grid.y selects A/W/epilogue),
//     2-phase double-buffered LDS pipeline (stage(next) issued before compute(cur))
//  3) chunk_sums (MFMA): per (nh,chunk): ST[e][d] = sum_s V[s][e]K[s][d] (bf16), z[d] = sum_s K[s][d] (f32)
//  4) scan_chunks: elementwise exclusive prefix over chunks (bf16 payload, f32 accum; z in f32)
//  5) attn_out: per (nh,chunk): A=tril(QK^T); out = (A V + Q S_prev) / (rowsum(A) + Q z_prev)

using bf16x8 = __attribute__((ext_vector_type(8))) short;
using u16x8  = __attribute__((ext_vector_type(8))) unsigned short;
using f32x4  = __attribute__((ext_vector_type(4))) float;

#define L_SEQ   8192
#define NCHUNK  128
#define RECB    8448   // bytes: 4096 bf16 ST + 64 f32 z

__device__ __forceinline__ float bf2f(unsigned short u) {
  union { unsigned int i; float f; } c; c.i = ((unsigned int)u) << 16; return c.f;
}
__device__ __forceinline__ unsigned short f2bf(float f) {
  union { float f; unsigned int i; } c; c.f = f;
  unsigned int r = c.i + 0x7fffu + ((c.i >> 16) & 1u);
  return (unsigned short)(r >> 16);
}
__device__ __forceinline__ float sp_(float x) {
  return (x > 20.0f) ? x : __logf(1.0f + __expf(x));
}
__device__ __forceinline__ void gll16(const void* g, void* l) {
  __builtin_amdgcn_global_load_lds(
      (const __attribute__((address_space(1))) unsigned int*)g,
      (__attribute__((address_space(3))) unsigned int*)l, 16, 0, 0);
}

// segment boundaries in float4 units:
//   q  [0,        4194304)   : 4*8192*512 floats / 4
//   k  [4194304,  8388608)
//   wq [8388608,  8454144)   : 512*512/4 = 65536 float4 each
//   wk [8454144,  8519680)
//   wv [8519680,  8585216)
__global__ void cvt_all(const float* __restrict__ q, const float* __restrict__ k,
                        const float* __restrict__ wq, const float* __restrict__ wk,
                        const float* __restrict__ wv,
                        unsigned short* __restrict__ qo, unsigned short* __restrict__ ko,
                        unsigned short* __restrict__ wqo, unsigned short* __restrict__ wko,
                        unsigned short* __restrict__ wvo) {
  const int stride = gridDim.x * blockDim.x;
  for (int i = blockIdx.x * blockDim.x + threadIdx.x; i < 8585216; i += stride) {
    const float* src; unsigned short* dst; int off;
    if (i < 4194304)      { src = q;  dst = qo;  off = i; }
    else if (i < 8388608) { src = k;  dst = ko;  off = i - 4194304; }
    else if (i < 8454144) { src = wq; dst = wqo; off = i - 8388608; }
    else if (i < 8519680) { src = wk; dst = wko; off = i - 8454144; }
    else                  { src = wv; dst = wvo; off = i - 8519680; }
    float4 v = ((const float4*)src)[off];
    ushort4 o;
    o.x = f2bf(v.x); o.y = f2bf(v.y); o.z = f2bf(v.z); o.w = f2bf(v.w);
    ((ushort4*)dst)[off] = o;
  }
}

// C[m][n] = sum_k A[m][k] * W[n][k]; per sub-GEMM M=32768, N=K=512. 128x128 tile, BK=64,
// 4 waves, double-buffered LDS, stage(next)-before-compute(cur) 2-phase pipeline.
// grid = (256, 12): y in [0,4) -> q-proj, [4,8) -> k-proj, [8,12) -> v-proj.
__global__ __launch_bounds__(256, 2) void gemm_all(const unsigned short* __restrict__ qbf,
                                                   const unsigned short* __restrict__ kbf,
                                                   const unsigned short* __restrict__ wqb,
                                                   const unsigned short* __restrict__ wkb,
                                                   const unsigned short* __restrict__ wvb,
                                                   unsigned short* __restrict__ qb,
                                                   unsigned short* __restrict__ kb,
                                                   unsigned short* __restrict__ vt) {
  __shared__ char Lds[65536];  // [buf][A:16K | B:16K]
  const int y = blockIdx.y;
  const unsigned short* A; const unsigned short* W; unsigned short* outp; int mode;
  if (y < 4)      { A = qbf; W = wqb; outp = qb; mode = 0; }
  else if (y < 8) { A = kbf; W = wkb; outp = kb; mode = 0; }
  else            { A = kbf; W = wvb; outp = vt; mode = 1; }
  const int bn = (y & 3) * 128;
  const int bm = blockIdx.x * 128;

  const int tid  = threadIdx.x;
  const int lane = tid & 63;
  const int wave = tid >> 6;
  const int l15  = lane & 15;
  const int lg   = lane >> 4;
  const int wr   = (wave >> 1) * 64;
  const int wc   = (wave & 1) * 64;
  const char* Abytes = (const char*)A;
  const char* Wbytes = (const char*)W;

  f32x4 acc[4][4] = {};

  // per-wave staging geometry (precomputed, ks-independent parts)
  const int p0 = wave * 4096 + lane * 16;

#define STAGE(buf, ks)                                                                   \
  {                                                                                      \
    char* Ab = Lds + (buf) * 32768;                                                      \
    char* Bb = Ab + 16384;                                                               \
    _Pragma("unroll")                                                                    \
    for (int it = 0; it < 4; ++it) {                                                     \
      const int p  = p0 + it * 1024;                                                     \
      const int r  = p >> 7;                                                             \
      const int cb = (p & 127) ^ ((r & 7) << 4);                                         \
      gll16(Abytes + (size_t)(bm + r) * 1024 + (ks) * 128 + cb, Ab + wave * 4096 + it * 1024); \
      gll16(Wbytes + (size_t)(bn + r) * 1024 + (ks) * 128 + cb, Bb + wave * 4096 + it * 1024); \
    }                                                                                    \
  }

  STAGE(0, 0);
  __syncthreads();   // drains vmcnt(0) before barrier (compiler-emitted)

  for (int ks = 0; ks < 8; ++ks) {
    const int cur = ks & 1;
    if (ks < 7) STAGE(cur ^ 1, ks + 1);   // issue next tile's loads, overlap with compute
    const char* Ab = Lds + cur * 32768;
    const char* Bb = Ab + 16384;
#pragma unroll
    for (int kk = 0; kk < 2; ++kk) {
      const int cb = kk * 64 + lg * 16;
      bf16x8 af[4], bw[4];
#pragma unroll
      for (int mi = 0; mi < 4; ++mi) {
        const int r = wr + mi * 16 + l15;
        af[mi] = *(const bf16x8*)(Ab + r * 128 + (cb ^ ((r & 7) << 4)));
      }
#pragma unroll
      for (int ni = 0; ni < 4; ++ni) {
        const int r = wc + ni * 16 + l15;
        bw[ni] = *(const bf16x8*)(Bb + r * 128 + (cb ^ ((r & 7) << 4)));
      }
#pragma unroll
      for (int mi = 0; mi < 4; ++mi)
#pragma unroll
        for (int ni = 0; ni < 4; ++ni)
          acc[mi][ni] = __builtin_amdgcn_mfma_f32_16x16x32_bf16(af[mi], bw[ni], acc[mi][ni], 0, 0, 0);
    }
    __syncthreads();  // waits vmcnt(0): next tile's loads had the whole compute phase in flight
  }
#undef STAGE

#pragma unroll
  for (int mi = 0; mi < 4; ++mi)
#pragma unroll
    for (int ni = 0; ni < 4; ++ni)
#pragma unroll
      for (int j = 0; j < 4; ++j) {
        const int m = bm + wr + mi * 16 + lg * 4 + j;
        const int n = bn + wc + ni * 16 + l15;
        float x = acc[mi][ni][j];
        const int nb = m >> 13;           // /8192
        const int l  = m & 8191;
        const int h  = n >> 6;
        if (mode == 0) {
          x = sp_(sp_(x));
          const int d = n & 63;
          outp[(((size_t)(nb * 8 + h) * 8192 + l) << 6) + d] = f2bf(x);
        } else {
          const int e = n & 63;
          const int cc = l >> 6, s = l & 63;
          outp[(((size_t)((nb * 8 + h) * 128 + cc) * 64 + e) << 6) + s] = f2bf(x);
        }
      }
}

// Per (nh, chunk): ST[e][d] = sum_s Vt[e][s]*K[s][d] via MFMA (in-LDS K transpose); z[d] = sum_s K[s][d]
__global__ __launch_bounds__(256, 4) void chunk_sums(const unsigned short* __restrict__ kb,
                                                     const unsigned short* __restrict__ vt,
                                                     char* __restrict__ S) {
  const int b  = blockIdx.x;          // nh*128 + c
  const int nh = b >> 7, c = b & 127;
  __shared__ char Kt[8192];    // [d][s] bf16, XOR-swizzled rows
  __shared__ char STs[8192];   // [e][d] bf16, linear
  const int tid = threadIdx.x, lane = tid & 63, wave = tid >> 6;
  const int l15 = lane & 15, lg = lane >> 4;
  const unsigned short* kch = kb + ((size_t)(nh * L_SEQ + c * 64) << 6);
  const unsigned short* vch = vt + ((size_t)b << 12);

  // transpose K chunk [s][d] -> Kt[d][s] (swizzled)
  {
    const int s = tid >> 2, d0 = (tid & 3) << 4;
    u16x8 a = *(const u16x8*)(kch + s * 64 + d0);
    u16x8 bb = *(const u16x8*)(kch + s * 64 + d0 + 8);
#pragma unroll
    for (int i = 0; i < 8; ++i) {
      const int d = d0 + i;
      *(unsigned short*)(Kt + d * 128 + ((2 * s) ^ ((d & 7) << 4))) = a[i];
    }
#pragma unroll
    for (int i = 0; i < 8; ++i) {
      const int d = d0 + 8 + i;
      *(unsigned short*)(Kt + d * 128 + ((2 * s) ^ ((d & 7) << 4))) = bb[i];
    }
  }
  __syncthreads();

  // MFMA: wave w -> e-rows 16w..16w+15 ; ST[e][d] = sum_s Vt[e][s]*Kt[d][s]
  f32x4 acc[4] = {};
#pragma unroll
  for (int kk = 0; kk < 2; ++kk) {
    bf16x8 av = *(const bf16x8*)(vch + (wave * 16 + l15) * 64 + kk * 32 + lg * 8);
#pragma unroll
    for (int ni = 0; ni < 4; ++ni) {
      const int d = ni * 16 + l15;
      bf16x8 bk = *(const bf16x8*)(Kt + d * 128 + ((kk * 64 + lg * 16) ^ ((d & 7) << 4)));
      acc[ni] = __builtin_amdgcn_mfma_f32_16x16x32_bf16(av, bk, acc[ni], 0, 0, 0);
    }
  }

  char* rec = S + (size_t)b * RECB;

  // z[d] = sum_s K[s][d] from Kt rows (f32)
  if (tid < 64) {
    float z = 0.f;
#pragma unroll
    for (int kk = 0; kk < 8; ++kk) {
      bf16x8 kv = *(const bf16x8*)(Kt + tid * 128 + ((kk * 16) ^ ((tid & 7) << 4)));
#pragma unroll
      for (int i = 0; i < 8; ++i) z += bf2f(kv[i]);
    }
    *(float*)(rec + 8192 + tid * 4) = z;
  }

  // stage ST to LDS (bf16), then coalesced copy-out
#pragma unroll
  for (int ni = 0; ni < 4; ++ni)
#pragma unroll
    for (int j = 0; j < 4; ++j) {
      const int e = wave * 16 + lg * 4 + j, d = ni * 16 + l15;
      *(unsigned short*)(STs + e * 128 + d * 2) = f2bf(acc[ni][j]);
    }
  __syncthreads();
  {
    const int off = tid * 32;
    *(u16x8*)(rec + off)      = *(const u16x8*)(STs + off);
    *(u16x8*)(rec + off + 16) = *(const u16x8*)(STs + off + 16);
  }
}

// Exclusive prefix over 128 chunks, in place. ST: bf16 payload, f32 accum (paired); z: f32.
__global__ void scan_chunks(char* __restrict__ S) {
  const int g = blockIdx.x * 256 + threadIdx.x;
  if (g < 65536) {                       // 32 nh * 2048 bf16-pairs
    const int nh = g >> 11, pr = g & 2047;
    char* p = S + (size_t)nh * NCHUNK * RECB + pr * 4;
    float a0 = 0.f, a1 = 0.f;
    for (int c = 0; c < NCHUNK; ++c) {
      const unsigned int u = *(unsigned int*)p;
      const float t0 = bf2f((unsigned short)(u & 0xffff));
      const float t1 = bf2f((unsigned short)(u >> 16));
      *(unsigned int*)p = (unsigned int)f2bf(a0) | ((unsigned int)f2bf(a1) << 16);
      a0 += t0; a1 += t1;
      p += RECB;
    }
  } else if (g < 67584) {                // 32 nh * 64 z floats
    const int idx = g - 65536;
    const int nh = idx >> 6, d = idx & 63;
    char* p = S + (size_t)nh * NCHUNK * RECB + 8192 + d * 4;
    float a = 0.f;
    for (int c = 0; c < NCHUNK; ++c) {
      const float t = *(float*)p; *(float*)p = a; a += t; p += RECB;
    }
  }
}

__global__ __launch_bounds__(256, 2) void attn_out(const unsigned short* __restrict__ qb,
                                                   const unsigned short* __restrict__ kb,
                                                   const unsigned short* __restrict__ vt,
                                                   const char* __restrict__ S,
                                                   float* __restrict__ out) {
  const int b  = blockIdx.x;
  const int nh = b >> 7, c = b & 127;
  const int nb = nh >> 3, h = nh & 7;
  __shared__ char Qs[8192], Ks[8192], Vs[8192], STs[8192], Ps[8192];
  __shared__ float zsh[64], dzh[64];
  const int tid = threadIdx.x, lane = tid & 63, wave = tid >> 6;
  const int l15 = lane & 15, lg = lane >> 4;

  const char* qch = (const char*)(qb + ((size_t)(nh * L_SEQ + c * 64) << 6));
  const char* kch = (const char*)(kb + ((size_t)(nh * L_SEQ + c * 64) << 6));
  const char* vch = (const char*)(vt + ((size_t)b << 12));
  const char* rb  = S + (size_t)b * RECB;

#pragma unroll
  for (int it = 0; it < 2; ++it) {
    const int p  = wave * 2048 + it * 1024 + lane * 16;
    const int r  = p >> 7;
    const int cb = (p & 127) ^ ((r & 7) << 4);
    const int src = r * 128 + cb;
    gll16(qch + src, Qs + wave * 2048 + it * 1024);
    gll16(kch + src, Ks + wave * 2048 + it * 1024);
    gll16(vch + src, Vs + wave * 2048 + it * 1024);
    gll16(rb + src,  STs + wave * 2048 + it * 1024);
  }
  if (tid < 64) zsh[tid] = *(const float*)(rb + 8192 + tid * 4);
  __syncthreads();

  // den_qz[t] = sum_d Q[t][d]*z_prev[d]
  {
    const int t = tid >> 2, p4 = tid & 3;
    float dq = 0.f;
#pragma unroll
    for (int half = 0; half < 2; ++half) {
      const int d0 = p4 * 16 + half * 8;
      const int cb = (d0 * 2) ^ ((t & 7) << 4);
      u16x8 qv = *(const u16x8*)(Qs + t * 128 + cb);
#pragma unroll
      for (int i = 0; i < 8; ++i) dq += bf2f(qv[i]) * zsh[d0 + i];
    }
    dq += __shfl_xor(dq, 1);
    dq += __shfl_xor(dq, 2);
    if (p4 == 0) dzh[t] = dq;
  }
  __syncthreads();

  // Phase 1: A = Q K^T (wave w owns rows 16w..16w+15)
  f32x4 accA[4] = {};
#pragma unroll
  for (int kk = 0; kk < 2; ++kk) {
    const int cb = kk * 64 + lg * 16;
    const int rq = wave * 16 + l15;
    bf16x8 aq = *(const bf16x8*)(Qs + rq * 128 + (cb ^ ((rq & 7) << 4)));
#pragma unroll
    for (int ni = 0; ni < 4; ++ni) {
      const int rk = ni * 16 + l15;
      bf16x8 bk = *(const bf16x8*)(Ks + rk * 128 + (cb ^ ((rk & 7) << 4)));
      accA[ni] = __builtin_amdgcn_mfma_f32_16x16x32_bf16(aq, bk, accA[ni], 0, 0, 0);
    }
  }

  // mask causal, rowsum (on bf16-rounded P for num/den consistency), write P
  float den4[4];
#pragma unroll
  for (int j = 0; j < 4; ++j) {
    const int t = wave * 16 + lg * 4 + j;
    float rs = 0.f;
#pragma unroll
    for (int ni = 0; ni < 4; ++ni) {
      const int s = ni * 16 + l15;
      const float v = (s <= t) ? accA[ni][j] : 0.f;
      const unsigned short pb = f2bf(v);
      rs += bf2f(pb);
      *(unsigned short*)(Ps + t * 128 + ((s * 2) ^ ((t & 7) << 4))) = pb;
    }
    rs += __shfl_xor(rs, 1);
    rs += __shfl_xor(rs, 2);
    rs += __shfl_xor(rs, 4);
    rs += __shfl_xor(rs, 8);
    den4[j] = rs + dzh[t];
  }
  __syncthreads();

  // Phase 2: num = P V + Q S_prev  (both B-operands bf16 rows, identical addressing)
  f32x4 accO[4] = {};
#pragma unroll
  for (int kk = 0; kk < 2; ++kk) {
    const int cb = kk * 64 + lg * 16;
    const int rp = wave * 16 + l15;
    bf16x8 ap = *(const bf16x8*)(Ps + rp * 128 + (cb ^ ((rp & 7) << 4)));
    bf16x8 aq = *(const bf16x8*)(Qs + rp * 128 + (cb ^ ((rp & 7) << 4)));
#pragma unroll
    for (int ni = 0; ni < 4; ++ni) {
      const int rv = ni * 16 + l15;
      bf16x8 bv = *(const bf16x8*)(Vs + rv * 128 + (cb ^ ((rv & 7) << 4)));
      bf16x8 bs = *(const bf16x8*)(STs + rv * 128 + (cb ^ ((rv & 7) << 4)));
      accO[ni] = __builtin_amdgcn_mfma_f32_16x16x32_bf16(ap, bv, accO[ni], 0, 0, 0);
      accO[ni] = __builtin_amdgcn_mfma_f32_16x16x32_bf16(aq, bs, accO[ni], 0, 0, 0);
    }
  }

#pragma unroll
  for (int ni = 0; ni < 4; ++ni) {
    const int e = ni * 16 + l15;
#pragma unroll
    for (int j = 0; j < 4; ++j) {
      const int t = wave * 16 + lg * 4 + j;
      out[((size_t)(nb * L_SEQ + c * 64 + t) << 9) + h * 64 + e] = accO[ni][j] / den4[j];
    }
  }
}

extern "C" void kernel_launch(void* const* d_in, const int* in_sizes, int n_in,
                              void* d_out, int out_size, void* d_ws, size_t ws_size,
                              hipStream_t stream) {
  (void)in_sizes; (void)n_in; (void)out_size; (void)ws_size;
  const float* query = (const float*)d_in[0];
  const float* key   = (const float*)d_in[1];
  const float* Wq    = (const float*)d_in[2];
  const float* Wk    = (const float*)d_in[3];
  const float* Wv    = (const float*)d_in[4];
  float* out = (float*)d_out;
  char* ws = (char*)d_ws;

  unsigned short* qb  = (unsigned short*)(ws);              // 33,554,432 B  (nh,l,d) bf16
  unsigned short* kb  = (unsigned short*)(ws + 33554432);   // 33,554,432 B
  unsigned short* vt  = (unsigned short*)(ws + 67108864);   // 33,554,432 B  (nh,c,e,s) bf16
  unsigned short* qbf = (unsigned short*)(ws + 100663296);  // 33,554,432 B  (dead after GEMMs)
  unsigned short* kbf = (unsigned short*)(ws + 134217728);  // 33,554,432 B  (dead after GEMMs)
  char*           Ssum = ws + 100663296;                    // 34,603,008 B  (aliased over qbf/kbf)
  unsigned short* wqb = (unsigned short*)(ws + 168820736);
  unsigned short* wkb = (unsigned short*)(ws + 169345024);
  unsigned short* wvb = (unsigned short*)(ws + 169869312);  // end: 170,393,600 B

  cvt_all<<<dim3(2048), dim3(256), 0, stream>>>(query, key, Wq, Wk, Wv, qbf, kbf, wqb, wkb, wvb);

  gemm_all<<<dim3(256, 12), dim3(256), 0, stream>>>(qbf, kbf, wqb, wkb, wvb, qb, kb, vt);

  chunk_sums<<<dim3(4096), dim3(256), 0, stream>>>(kb, vt, Ssum);
  scan_chunks<<<dim3(264), dim3(256), 0, stream>>>(Ssum);
  attn_out<<<dim3(4096), dim3(256), 0, stream>>>(qb, kb, vt, Ssum, out);
}

// Round 5
// 233.841 us; speedup vs baseline: 1.0070x; 1.0070x over previous
//
#include <hip/hip_runtime.h>

// Pipeline:
//  1) cvt_all: query,key,Wq,Wk,Wv f32 -> bf16 (single launch)
//  2) gemm_stream: all 3 projections, W-panel persistent in LDS (128 KB, swizzled),
//     A streamed global->VGPR, barrier-free MFMA main loop. grid.x/256 selects sub-GEMM.
//  3) chunk_sums (MFMA): per (nh,chunk): ST[e][d] = sum_s V[s][e]K[s][d] (bf16), z[d] (f32)
//  4) scan_chunks: exclusive prefix over chunks (bf16 payload, f32 accum; z f32)
//  5) attn_out: per (nh,chunk): A=tril(QK^T); out = (A V + Q S_prev) / (rowsum(A) + Q z_prev)

using bf16x8 = __attribute__((ext_vector_type(8))) short;
using u16x8  = __attribute__((ext_vector_type(8))) unsigned short;
using f32x4  = __attribute__((ext_vector_type(4))) float;

#define L_SEQ   8192
#define NCHUNK  128
#define RECB    8448   // bytes: 4096 bf16 ST + 64 f32 z

__device__ __forceinline__ float bf2f(unsigned short u) {
  union { unsigned int i; float f; } c; c.i = ((unsigned int)u) << 16; return c.f;
}
__device__ __forceinline__ unsigned short f2bf(float f) {
  union { float f; unsigned int i; } c; c.f = f;
  unsigned int r = c.i + 0x7fffu + ((c.i >> 16) & 1u);
  return (unsigned short)(r >> 16);
}
__device__ __forceinline__ float sp_(float x) {
  return (x > 20.0f) ? x : __logf(1.0f + __expf(x));
}
__device__ __forceinline__ void gll16(const void* g, void* l) {
  __builtin_amdgcn_global_load_lds(
      (const __attribute__((address_space(1))) unsigned int*)g,
      (__attribute__((address_space(3))) unsigned int*)l, 16, 0, 0);
}

// segment boundaries in float4 units:
//   q  [0,        4194304)
//   k  [4194304,  8388608)
//   wq [8388608,  8454144)   : 512*512/4 = 65536 float4 each
//   wk [8454144,  8519680)
//   wv [8519680,  8585216)
__global__ void cvt_all(const float* __restrict__ q, const float* __restrict__ k,
                        const float* __restrict__ wq, const float* __restrict__ wk,
                        const float* __restrict__ wv,
                        unsigned short* __restrict__ qo, unsigned short* __restrict__ ko,
                        unsigned short* __restrict__ wqo, unsigned short* __restrict__ wko,
                        unsigned short* __restrict__ wvo) {
  const int stride = gridDim.x * blockDim.x;
  for (int i = blockIdx.x * blockDim.x + threadIdx.x; i < 8585216; i += stride) {
    const float* src; unsigned short* dst; int off;
    if (i < 4194304)      { src = q;  dst = qo;  off = i; }
    else if (i < 8388608) { src = k;  dst = ko;  off = i - 4194304; }
    else if (i < 8454144) { src = wq; dst = wqo; off = i - 8388608; }
    else if (i < 8519680) { src = wk; dst = wko; off = i - 8454144; }
    else                  { src = wv; dst = wvo; off = i - 8519680; }
    float4 v = ((const float4*)src)[off];
    ushort4 o;
    o.x = f2bf(v.x); o.y = f2bf(v.y); o.z = f2bf(v.z); o.w = f2bf(v.w);
    ((ushort4*)dst)[off] = o;
  }
}

// C[m][n] = sum_k A[m][k]*W[n][k]; per sub-GEMM M=32768, N=K=512.
// Block: 512 thr (8 waves), owns 512 rows x 128-col panel. W-panel 128 KB persistent
// in LDS (XOR-swizzled, loaded once). A streamed global->VGPR. No barriers in K-loop.
// grid.x = 768: [0,256) q-proj, [256,512) k-proj, [512,768) v-proj.
// XCD swizzle: b=g&255 -> xcd=b&7, t=b>>3, mchunk=xcd+ (t>>2)*8, panel=t&3
//   => each XCD gets 8 m-chunks shared by its 4 panels: 8*512rows*1KB = 4 MB = L2.
__global__ __launch_bounds__(512, 2) void gemm_stream(const unsigned short* __restrict__ qbf,
                                                      const unsigned short* __restrict__ kbf,
                                                      const unsigned short* __restrict__ wqb,
                                                      const unsigned short* __restrict__ wkb,
                                                      const unsigned short* __restrict__ wvb,
                                                      unsigned short* __restrict__ qb,
                                                      unsigned short* __restrict__ kb,
                                                      unsigned short* __restrict__ vt) {
  __shared__ char Ws[131072];   // [col 0..127][k-bytes 0..1023], swizzled
  const int g = blockIdx.x, sub = g >> 8, b = g & 255;
  const int xcd = b & 7, t = b >> 3;
  const int bm = (xcd + (t >> 2) * 8) * 512;
  const int bn = (t & 3) * 128;

  const unsigned short* A; const unsigned short* W; unsigned short* outp; int mode;
  if (sub == 0)      { A = qbf; W = wqb; outp = qb; mode = 0; }
  else if (sub == 1) { A = kbf; W = wkb; outp = kb; mode = 0; }
  else               { A = kbf; W = wvb; outp = vt; mode = 1; }

  const int tid = threadIdx.x, lane = tid & 63, wv = tid >> 6;
  const int l15 = lane & 15, lg = lane >> 4;

  // stage W panel: linear LDS dest, pre-swizzled global source
  const char* Wb = (const char*)W;
#pragma unroll
  for (int it = 0; it < 16; ++it) {
    const int p = it * 8192 + tid * 16;
    const int col = p >> 10, kb2 = p & 1023;
    gll16(Wb + (size_t)(bn + col) * 1024 + (kb2 ^ ((col & 7) << 4)),
          Ws + it * 8192 + wv * 1024);
  }
  __syncthreads();

  const char* Ab = (const char*)A + (size_t)(bm + wv * 64 + l15) * 1024 + lg * 16;

  f32x4 acc[4][8] = {};
  bf16x8 aC[4], aN[4];
#pragma unroll
  for (int rg = 0; rg < 4; ++rg) aC[rg] = *(const bf16x8*)(Ab + rg * 16384);

#pragma unroll 1
  for (int kk = 0; kk < 16; ++kk) {
    if (kk < 15) {
#pragma unroll
      for (int rg = 0; rg < 4; ++rg)
        aN[rg] = *(const bf16x8*)(Ab + rg * 16384 + (kk + 1) * 64);
    }
    bf16x8 bf[8];
#pragma unroll
    for (int cf = 0; cf < 8; ++cf) {
      const int col = cf * 16 + l15;
      bf[cf] = *(const bf16x8*)(Ws + col * 1024 + ((kk * 64 + lg * 16) ^ ((col & 7) << 4)));
    }
#pragma unroll
    for (int rg = 0; rg < 4; ++rg)
#pragma unroll
      for (int cf = 0; cf < 8; ++cf)
        acc[rg][cf] = __builtin_amdgcn_mfma_f32_16x16x32_bf16(aC[rg], bf[cf], acc[rg][cf], 0, 0, 0);
    if (kk < 15) {
#pragma unroll
      for (int rg = 0; rg < 4; ++rg) aC[rg] = aN[rg];
    }
  }

#pragma unroll
  for (int rg = 0; rg < 4; ++rg)
#pragma unroll
    for (int cf = 0; cf < 8; ++cf)
#pragma unroll
      for (int j = 0; j < 4; ++j) {
        const int m = bm + wv * 64 + rg * 16 + lg * 4 + j;
        const int n = bn + cf * 16 + l15;
        float x = acc[rg][cf][j];
        const int nb = m >> 13;
        const int l  = m & 8191;
        const int h  = n >> 6;
        if (mode == 0) {
          x = sp_(sp_(x));
          const int d = n & 63;
          outp[(((size_t)(nb * 8 + h) * 8192 + l) << 6) + d] = f2bf(x);
        } else {
          const int e = n & 63;
          const int cc = l >> 6, s = l & 63;
          outp[(((size_t)((nb * 8 + h) * 128 + cc) * 64 + e) << 6) + s] = f2bf(x);
        }
      }
}

// Per (nh, chunk): ST[e][d] = sum_s Vt[e][s]*K[s][d] via MFMA (in-LDS K transpose); z[d] = sum_s K[s][d]
__global__ __launch_bounds__(256, 4) void chunk_sums(const unsigned short* __restrict__ kb,
                                                     const unsigned short* __restrict__ vt,
                                                     char* __restrict__ S) {
  const int b  = blockIdx.x;          // nh*128 + c
  const int nh = b >> 7, c = b & 127;
  __shared__ char Kt[8192];    // [d][s] bf16, XOR-swizzled rows
  __shared__ char STs[8192];   // [e][d] bf16, linear
  const int tid = threadIdx.x, lane = tid & 63, wave = tid >> 6;
  const int l15 = lane & 15, lg = lane >> 4;
  const unsigned short* kch = kb + ((size_t)(nh * L_SEQ + c * 64) << 6);
  const unsigned short* vch = vt + ((size_t)b << 12);

  // transpose K chunk [s][d] -> Kt[d][s] (swizzled)
  {
    const int s = tid >> 2, d0 = (tid & 3) << 4;
    u16x8 a = *(const u16x8*)(kch + s * 64 + d0);
    u16x8 bb = *(const u16x8*)(kch + s * 64 + d0 + 8);
#pragma unroll
    for (int i = 0; i < 8; ++i) {
      const int d = d0 + i;
      *(unsigned short*)(Kt + d * 128 + ((2 * s) ^ ((d & 7) << 4))) = a[i];
    }
#pragma unroll
    for (int i = 0; i < 8; ++i) {
      const int d = d0 + 8 + i;
      *(unsigned short*)(Kt + d * 128 + ((2 * s) ^ ((d & 7) << 4))) = bb[i];
    }
  }
  __syncthreads();

  // MFMA: wave w -> e-rows 16w..16w+15 ; ST[e][d] = sum_s Vt[e][s]*Kt[d][s]
  f32x4 acc[4] = {};
#pragma unroll
  for (int kk = 0; kk < 2; ++kk) {
    bf16x8 av = *(const bf16x8*)(vch + (wave * 16 + l15) * 64 + kk * 32 + lg * 8);
#pragma unroll
    for (int ni = 0; ni < 4; ++ni) {
      const int d = ni * 16 + l15;
      bf16x8 bk = *(const bf16x8*)(Kt + d * 128 + ((kk * 64 + lg * 16) ^ ((d & 7) << 4)));
      acc[ni] = __builtin_amdgcn_mfma_f32_16x16x32_bf16(av, bk, acc[ni], 0, 0, 0);
    }
  }

  char* rec = S + (size_t)b * RECB;

  // z[d] = sum_s K[s][d] from Kt rows (f32)
  if (tid < 64) {
    float z = 0.f;
#pragma unroll
    for (int kk = 0; kk < 8; ++kk) {
      bf16x8 kv = *(const bf16x8*)(Kt + tid * 128 + ((kk * 16) ^ ((tid & 7) << 4)));
#pragma unroll
      for (int i = 0; i < 8; ++i) z += bf2f(kv[i]);
    }
    *(float*)(rec + 8192 + tid * 4) = z;
  }

  // stage ST to LDS (bf16), then coalesced copy-out
#pragma unroll
  for (int ni = 0; ni < 4; ++ni)
#pragma unroll
    for (int j = 0; j < 4; ++j) {
      const int e = wave * 16 + lg * 4 + j, d = ni * 16 + l15;
      *(unsigned short*)(STs + e * 128 + d * 2) = f2bf(acc[ni][j]);
    }
  __syncthreads();
  {
    const int off = tid * 32;
    *(u16x8*)(rec + off)      = *(const u16x8*)(STs + off);
    *(u16x8*)(rec + off + 16) = *(const u16x8*)(STs + off + 16);
  }
}

// Exclusive prefix over 128 chunks, in place. ST: bf16 payload, f32 accum (paired); z: f32.
__global__ void scan_chunks(char* __restrict__ S) {
  const int g = blockIdx.x * 256 + threadIdx.x;
  if (g < 65536) {                       // 32 nh * 2048 bf16-pairs
    const int nh = g >> 11, pr = g & 2047;
    char* p = S + (size_t)nh * NCHUNK * RECB + pr * 4;
    float a0 = 0.f, a1 = 0.f;
    for (int c = 0; c < NCHUNK; ++c) {
      const unsigned int u = *(unsigned int*)p;
      const float t0 = bf2f((unsigned short)(u & 0xffff));
      const float t1 = bf2f((unsigned short)(u >> 16));
      *(unsigned int*)p = (unsigned int)f2bf(a0) | ((unsigned int)f2bf(a1) << 16);
      a0 += t0; a1 += t1;
      p += RECB;
    }
  } else if (g < 67584) {                // 32 nh * 64 z floats
    const int idx = g - 65536;
    const int nh = idx >> 6, d = idx & 63;
    char* p = S + (size_t)nh * NCHUNK * RECB + 8192 + d * 4;
    float a = 0.f;
    for (int c = 0; c < NCHUNK; ++c) {
      const float t = *(float*)p; *(float*)p = a; a += t; p += RECB;
    }
  }
}

__global__ __launch_bounds__(256, 2) void attn_out(const unsigned short* __restrict__ qb,
                                                   const unsigned short* __restrict__ kb,
                                                   const unsigned short* __restrict__ vt,
                                                   const char* __restrict__ S,
                                                   float* __restrict__ out) {
  const int b  = blockIdx.x;
  const int nh = b >> 7, c = b & 127;
  const int nb = nh >> 3, h = nh & 7;
  __shared__ char Qs[8192], Ks[8192], Vs[8192], STs[8192], Ps[8192];
  __shared__ float zsh[64], dzh[64];
  const int tid = threadIdx.x, lane = tid & 63, wave = tid >> 6;
  const int l15 = lane & 15, lg = lane >> 4;

  const char* qch = (const char*)(qb + ((size_t)(nh * L_SEQ + c * 64) << 6));
  const char* kch = (const char*)(kb + ((size_t)(nh * L_SEQ + c * 64) << 6));
  const char* vch = (const char*)(vt + ((size_t)b << 12));
  const char* rb  = S + (size_t)b * RECB;

#pragma unroll
  for (int it = 0; it < 2; ++it) {
    const int p  = wave * 2048 + it * 1024 + lane * 16;
    const int r  = p >> 7;
    const int cb = (p & 127) ^ ((r & 7) << 4);
    const int src = r * 128 + cb;
    gll16(qch + src, Qs + wave * 2048 + it * 1024);
    gll16(kch + src, Ks + wave * 2048 + it * 1024);
    gll16(vch + src, Vs + wave * 2048 + it * 1024);
    gll16(rb + src,  STs + wave * 2048 + it * 1024);
  }
  if (tid < 64) zsh[tid] = *(const float*)(rb + 8192 + tid * 4);
  __syncthreads();

  // den_qz[t] = sum_d Q[t][d]*z_prev[d]
  {
    const int t = tid >> 2, p4 = tid & 3;
    float dq = 0.f;
#pragma unroll
    for (int half = 0; half < 2; ++half) {
      const int d0 = p4 * 16 + half * 8;
      const int cb = (d0 * 2) ^ ((t & 7) << 4);
      u16x8 qv = *(const u16x8*)(Qs + t * 128 + cb);
#pragma unroll
      for (int i = 0; i < 8; ++i) dq += bf2f(qv[i]) * zsh[d0 + i];
    }
    dq += __shfl_xor(dq, 1);
    dq += __shfl_xor(dq, 2);
    if (p4 == 0) dzh[t] = dq;
  }
  __syncthreads();

  // Phase 1: A = Q K^T (wave w owns rows 16w..16w+15)
  f32x4 accA[4] = {};
#pragma unroll
  for (int kk = 0; kk < 2; ++kk) {
    const int cb = kk * 64 + lg * 16;
    const int rq = wave * 16 + l15;
    bf16x8 aq = *(const bf16x8*)(Qs + rq * 128 + (cb ^ ((rq & 7) << 4)));
#pragma unroll
    for (int ni = 0; ni < 4; ++ni) {
      const int rk = ni * 16 + l15;
      bf16x8 bk = *(const bf16x8*)(Ks + rk * 128 + (cb ^ ((rk & 7) << 4)));
      accA[ni] = __builtin_amdgcn_mfma_f32_16x16x32_bf16(aq, bk, accA[ni], 0, 0, 0);
    }
  }

  // mask causal, rowsum (on bf16-rounded P for num/den consistency), write P
  float den4[4];
#pragma unroll
  for (int j = 0; j < 4; ++j) {
    const int t = wave * 16 + lg * 4 + j;
    float rs = 0.f;
#pragma unroll
    for (int ni = 0; ni < 4; ++ni) {
      const int s = ni * 16 + l15;
      const float v = (s <= t) ? accA[ni][j] : 0.f;
      const unsigned short pb = f2bf(v);
      rs += bf2f(pb);
      *(unsigned short*)(Ps + t * 128 + ((s * 2) ^ ((t & 7) << 4))) = pb;
    }
    rs += __shfl_xor(rs, 1);
    rs += __shfl_xor(rs, 2);
    rs += __shfl_xor(rs, 4);
    rs += __shfl_xor(rs, 8);
    den4[j] = rs + dzh[t];
  }
  __syncthreads();

  // Phase 2: num = P V + Q S_prev  (both B-operands bf16 rows, identical addressing)
  f32x4 accO[4] = {};
#pragma unroll
  for (int kk = 0; kk < 2; ++kk) {
    const int cb = kk * 64 + lg * 16;
    const int rp = wave * 16 + l15;
    bf16x8 ap = *(const bf16x8*)(Ps + rp * 128 + (cb ^ ((rp & 7) << 4)));
    bf16x8 aq = *(const bf16x8*)(Qs + rp * 128 + (cb ^ ((rp & 7) << 4)));
#pragma unroll
    for (int ni = 0; ni < 4; ++ni) {
      const int rv = ni * 16 + l15;
      bf16x8 bv = *(const bf16x8*)(Vs + rv * 128 + (cb ^ ((rv & 7) << 4)));
      bf16x8 bs = *(const bf16x8*)(STs + rv * 128 + (cb ^ ((rv & 7) << 4)));
      accO[ni] = __builtin_amdgcn_mfma_f32_16x16x32_bf16(ap, bv, accO[ni], 0, 0, 0);
      accO[ni] = __builtin_amdgcn_mfma_f32_16x16x32_bf16(aq, bs, accO[ni], 0, 0, 0);
    }
  }

#pragma unroll
  for (int ni = 0; ni < 4; ++ni) {
    const int e = ni * 16 + l15;
#pragma unroll
    for (int j = 0; j < 4; ++j) {
      const int t = wave * 16 + lg * 4 + j;
      out[((size_t)(nb * L_SEQ + c * 64 + t) << 9) + h * 64 + e] = accO[ni][j] / den4[j];
    }
  }
}

extern "C" void kernel_launch(void* const* d_in, const int* in_sizes, int n_in,
                              void* d_out, int out_size, void* d_ws, size_t ws_size,
                              hipStream_t stream) {
  (void)in_sizes; (void)n_in; (void)out_size; (void)ws_size;
  const float* query = (const float*)d_in[0];
  const float* key   = (const float*)d_in[1];
  const float* Wq    = (const float*)d_in[2];
  const float* Wk    = (const float*)d_in[3];
  const float* Wv    = (const float*)d_in[4];
  float* out = (float*)d_out;
  char* ws = (char*)d_ws;

  unsigned short* qb  = (unsigned short*)(ws);              // 33,554,432 B  (nh,l,d) bf16
  unsigned short* kb  = (unsigned short*)(ws + 33554432);   // 33,554,432 B
  unsigned short* vt  = (unsigned short*)(ws + 67108864);   // 33,554,432 B  (nh,c,e,s) bf16
  unsigned short* qbf = (unsigned short*)(ws + 100663296);  // 33,554,432 B  (dead after GEMMs)
  unsigned short* kbf = (unsigned short*)(ws + 134217728);  // 33,554,432 B  (dead after GEMMs)
  char*           Ssum = ws + 100663296;                    // 34,603,008 B  (aliased over qbf/kbf)
  unsigned short* wqb = (unsigned short*)(ws + 168820736);
  unsigned short* wkb = (unsigned short*)(ws + 169345024);
  unsigned short* wvb = (unsigned short*)(ws + 169869312);  // end: 170,393,600 B

  cvt_all<<<dim3(2048), dim3(256), 0, stream>>>(query, key, Wq, Wk, Wv, qbf, kbf, wqb, wkb, wvb);

  gemm_stream<<<dim3(768), dim3(512), 0, stream>>>(qbf, kbf, wqb, wkb, wvb, qb, kb, vt);

  chunk_sums<<<dim3(4096), dim3(256), 0, stream>>>(kb, vt, Ssum);
  scan_chunks<<<dim3(264), dim3(256), 0, stream>>>(Ssum);
  attn_out<<<dim3(4096), dim3(256), 0, stream>>>(qb, kb, vt, Ssum, out);
}